// Round 8
// baseline (942.970 us; speedup 1.0000x reference)
//
#include <hip/hip_runtime.h>
#include <hip/hip_bf16.h>

// B=8, N=4096, D=H=256. out[b,h] = sum_k w[b,k]*V[b,k,h],
//   w[b,k] = (1/N) sum_q exp(scale*s_qk)/l_q,  l_q = sum_k exp(scale*s_qk)
// R18: A-fragments parked in AGPRs via v_accvgpr_write/read inline asm;
//      MFMA stays a BUILTIN (R17's raw-asm MFMA broke — hazard recognizer
//      can't see MFMAs inside asm strings). Budget at (512,2) = 256/wave:
//      AGPR 128 (A) + 32 (acc), arch ~90-110 (rs 32 + bb<=16 + addr) < 128
//      cap -> no spill. st-loop unroll capped at 4 to bound bb liveness;
//      volatile asm pins per-use AGPR->VGPR reads (no bulk hoist).
//      Structure otherwise = R16/R15 (64 A-rows/wave, 1 B-read : 2 MFMA,
//      16-tile stream, 1 barrier/tile). qkv/convert/finalize verbatim.

#define NTOK 4096
#define HDIM 256
#define NBATCH 8
#define SCALE 0.0625f  // 1/sqrt(256)

typedef __attribute__((ext_vector_type(8))) short short8_t;   // 8 bf16 (4 VGPRs)
typedef __attribute__((ext_vector_type(16))) float f32x16;    // 32x32 C/D frag

__device__ __forceinline__ unsigned short f2bf(float f) {
    unsigned u = __float_as_uint(f);
    u += 0x7fff + ((u >> 16) & 1);   // RNE
    return (unsigned short)(u >> 16);
}

#define MFMA(a, b, c) __builtin_amdgcn_mfma_f32_32x32x16_bf16(a, b, c, 0, 0, 0)

// ---- AGPR storage primitives: value round-trips through the accumulator file.
__device__ __forceinline__ unsigned ag_w(unsigned v) {
    unsigned d;
    asm volatile("v_accvgpr_write_b32 %0, %1" : "=a"(d) : "v"(v));
    return d;
}
__device__ __forceinline__ unsigned ag_r(unsigned a) {
    unsigned d;
    asm volatile("v_accvgpr_read_b32 %0, %1" : "=v"(d) : "a"(a));
    return d;
}
// store one 16B A-frag (4 words) into AGPR-class values
__device__ __forceinline__ void sta4(unsigned* dst, short8_t v) {
    union { short8_t s; unsigned u[4]; } t;
    t.s = v;
    dst[0] = ag_w(t.u[0]); dst[1] = ag_w(t.u[1]);
    dst[2] = ag_w(t.u[2]); dst[3] = ag_w(t.u[3]);
}
// load one 16B A-frag back to VGPRs
__device__ __forceinline__ short8_t lda4(unsigned a0, unsigned a1, unsigned a2, unsigned a3) {
    union { unsigned u[4]; short8_t s; } d;
    d.u[0] = ag_r(a0); d.u[1] = ag_r(a1); d.u[2] = ag_r(a2); d.u[3] = ag_r(a3);
    return d.s;
}

__device__ __forceinline__ void async_cp16(const void* g, void* l) {
    __builtin_amdgcn_global_load_lds((const __attribute__((address_space(1))) void*)g,
                                     (__attribute__((address_space(3))) void*)l, 16, 0, 0);
}

// ---- validated 128-row stager (used by qkv_mfma): 16B unit (r,u) -> r*8 + (u^(r&7))
__device__ __forceinline__ void stage_swz(unsigned short* lds, const unsigned short* src,
                                          int row0, int dbase, int w, int l) {
#pragma unroll
    for (int i = 0; i < 4; ++i) {
        int rloc = w * 32 + i * 8 + (l >> 3);
        int u = (l & 7) ^ (l >> 3);
        const unsigned short* g = src + (size_t)(row0 + rloc) * HDIM + dbase + u * 8;
        unsigned short* d = lds + (w * 32 + i * 8) * 64;
        async_cp16(g, d);
    }
}

__device__ __forceinline__ short8_t frd(const unsigned short* lds, int rb, int lo, int u) {
    return *(const short8_t*)(lds + ((rb * 32 + lo) * 8 + (u ^ (lo & 7))) * 8);
}

// ---- 64-row x 256-col bf16 tile stager (32KB), layout [dc][row][unit'],
//      unit' = u ^ (row&7). Per-lane element offsets precomputed in soff[4].
__device__ __forceinline__ void stage64(unsigned short* lds, const unsigned short* src,
                                        int w, const int* soff) {
#pragma unroll
    for (int j = 0; j < 4; ++j)
        async_cp16(src + soff[j], lds + (size_t)(w * 4 + j) * 512);
}

// read B-frag: row r (0..63) of resident tile, depth unit u (0..31)
__device__ __forceinline__ short8_t krd(const unsigned short* lds, int r, int u) {
    int dc = u >> 3, uu = u & 7;
    return *(const short8_t*)(lds + ((dc * 64 + r) * 8 + (uu ^ (r & 7))) * 8);
}

__global__ void zero_kernel(float* __restrict__ w, float* __restrict__ l, float* __restrict__ out) {
    int i = blockIdx.x * 256 + threadIdx.x;
    w[i] = 0.f;
    l[i] = 0.f;
    if (i < NBATCH * HDIM) out[i] = 0.f;
}

// ---------------- fp32 -> bf16 for x (once) ----------------
__global__ void convert_x(const float* __restrict__ x, unsigned short* __restrict__ xbf) {
    int i = (blockIdx.x * 256 + threadIdx.x) * 4;
    float4 v = *(const float4*)(x + i);
    ushort4 o;
    o.x = f2bf(v.x); o.y = f2bf(v.y); o.z = f2bf(v.z); o.w = f2bf(v.w);
    *(ushort4*)(xbf + i) = o;
}

__global__ void convert_wt(const float* __restrict__ Wq, const float* __restrict__ Wk,
                           const float* __restrict__ Wv, unsigned short* __restrict__ Wt) {
    int z = blockIdx.y;
    const float* W = (z == 0) ? Wq : (z == 1) ? Wk : Wv;
    unsigned short* o = Wt + z * 65536;
    int n = threadIdx.x;
    for (int kk = 0; kk < 32; ++kk) {
        int k = blockIdx.x * 32 + kk;
        o[n * 256 + k] = f2bf(W[k * 256 + n]);
    }
}

// ---------------- QKV projection (verbatim validated) ----------------
__global__ __launch_bounds__(256) void qkv_mfma(const unsigned short* __restrict__ xbf,
                                                const unsigned short* __restrict__ Wt,
                                                const float* __restrict__ bq, const float* __restrict__ bk,
                                                const float* __restrict__ bv,
                                                unsigned short* __restrict__ Qbf,
                                                unsigned short* __restrict__ Kbf,
                                                float* __restrict__ Vf) {
    const int z = blockIdx.z;
    const unsigned short* Wz = Wt + z * 65536;
    const float* bias = (z == 0) ? bq : (z == 1) ? bk : bv;
    const int m0 = blockIdx.x * 128, n0 = blockIdx.y * 128;
    const int t = threadIdx.x, w = t >> 6, l = t & 63, lo = l & 31, hi = l >> 5;
    const int rm = (w & 1) * 2, rn = (w >> 1) * 2;

    __shared__ __align__(16) char smem[32768];   // Xb 16K | Wb 16K
    unsigned short* Xb = (unsigned short*)smem;
    unsigned short* Wb = (unsigned short*)(smem + 16384);

    f32x16 acc[2][2];
#pragma unroll
    for (int a = 0; a < 2; ++a)
#pragma unroll
        for (int c = 0; c < 2; ++c)
#pragma unroll
            for (int r = 0; r < 16; ++r) acc[a][c][r] = 0.f;

    for (int dc = 0; dc < 4; ++dc) {
        __syncthreads();
        stage_swz(Xb, xbf, m0, dc * 64, w, l);
        stage_swz(Wb, Wz, n0, dc * 64, w, l);
        __syncthreads();
#pragma unroll
        for (int ks = 0; ks < 4; ++ks) {
            int u = ks * 2 + hi;
            short8_t a0 = frd(Xb, rm + 0, lo, u);
            short8_t a1 = frd(Xb, rm + 1, lo, u);
            short8_t b0 = frd(Wb, rn + 0, lo, u);
            short8_t b1 = frd(Wb, rn + 1, lo, u);
            acc[0][0] = MFMA(a0, b0, acc[0][0]);
            acc[0][1] = MFMA(a0, b1, acc[0][1]);
            acc[1][0] = MFMA(a1, b0, acc[1][0]);
            acc[1][1] = MFMA(a1, b1, acc[1][1]);
        }
    }
    float bc0 = bias[n0 + (w >> 1) * 64 + lo];
    float bc1 = bias[n0 + (w >> 1) * 64 + 32 + lo];
#pragma unroll
    for (int mb = 0; mb < 2; ++mb)
#pragma unroll
        for (int r = 0; r < 16; ++r) {
            int row = m0 + (w & 1) * 64 + mb * 32 + (r & 3) + 8 * (r >> 2) + 4 * hi;
            int c0 = n0 + (w >> 1) * 64 + lo, c1 = c0 + 32;
            float v0 = acc[mb][0][r] + bc0;
            float v1 = acc[mb][1][r] + bc1;
            if (z == 2) {
                Vf[(size_t)row * HDIM + c0] = v0;
                Vf[(size_t)row * HDIM + c1] = v1;
            } else {
                unsigned short* o = (z == 0) ? Qbf : Kbf;
                o[(size_t)row * HDIM + c0] = f2bf(v0);
                o[(size_t)row * HDIM + c1] = f2bf(v1);
            }
        }
}

// ---------------- pass 1 (R18): l[b,q] = sum_k exp(scale*s) ----------------
// Block: 512 thr / 8 waves. Wave w owns 64 q-rows; A-frags live in AGPRs
// (v_accvgpr_write at prologue, per-use v_accvgpr_read in the loop).
// Streams 1024 K-rows in 16 tiles of 64 (LDS dbuf), 1 barrier per tile.
__global__ __launch_bounds__(512, 2) void score_pass1(const unsigned short* __restrict__ Qbf,
                                                      const unsigned short* __restrict__ Kbf,
                                                      float* __restrict__ lsum) {
    // XCD-chunked remap: the 8 q-tile blocks sharing one (kslice,b) K-stream
    // land on one XCD (ids congruent mod 8) -> stream re-reads are L2-hits.
    const int id = blockIdx.x;
    const int xcd = id & 7, j = id >> 3;        // j in 0..31
    const int qtile = j & 7, gh = j >> 3;       // gh in 0..3
    const int g = xcd * 4 + gh;                 // group 0..31
    const int kslice = g & 3, b = g >> 2;

    const int q0 = qtile * 512;
    const int kbase = kslice * 1024;
    const int t = threadIdx.x, w = t >> 6, l = t & 63, lo = l & 31, hi = l >> 5;
    const unsigned short* Qb = Qbf + (size_t)b * NTOK * HDIM;
    const unsigned short* Kb = Kbf + (size_t)b * NTOK * HDIM;

    __shared__ __align__(16) unsigned short Kbuf[2][16384];   // 2 x 32KB

    // per-lane stage offsets (elements), constant across tiles
    int soff[4];
#pragma unroll
    for (int jj = 0; jj < 4; ++jj) {
        int idx = (w * 4 + jj) * 64 + l;
        int r = (idx >> 3) & 63, dc = idx >> 9;
        int u = (idx & 7) ^ (r & 7);
        soff[jj] = r * HDIM + dc * 64 + u * 8;
    }

    const unsigned short* src = Kb + (size_t)kbase * HDIM;
    stage64(Kbuf[0], src, w, soff);                            // tile 0 in flight
    src += 64 * HDIM;

    // A-frags: 64 q-rows x 256 depth -> AGPR file. A0 = rows q0+w*64+lo, A1 = +32.
    unsigned A0g[16][4], A1g[16][4];
    const unsigned short* qrow = Qb + (size_t)(q0 + w * 64 + lo) * HDIM + hi * 8;
#pragma unroll
    for (int st = 0; st < 16; ++st) {
        sta4(A0g[st], *(const short8_t*)(qrow + st * 16));
        sta4(A1g[st], *(const short8_t*)(qrow + 32 * HDIM + st * 16));
    }

    float rs0[16], rs1[16];
#pragma unroll
    for (int r = 0; r < 16; ++r) { rs0[r] = 0.f; rs1[r] = 0.f; }

    __syncthreads();   // drains tile-0 stage + A-loads

    int cur = 0;
    for (int kt = 0; kt < 16; ++kt) {
        if (kt < 15) { stage64(Kbuf[cur ^ 1], src, w, soff); src += 64 * HDIM; }
        const unsigned short* KL = Kbuf[cur];
#pragma unroll
        for (int h = 0; h < 2; ++h) {
            const int rr = h * 32 + lo;
            f32x16 acc0 = {}, acc1 = {};
#pragma unroll 4
            for (int st = 0; st < 16; ++st) {
                short8_t a0 = lda4(A0g[st][0], A0g[st][1], A0g[st][2], A0g[st][3]);
                short8_t a1 = lda4(A1g[st][0], A1g[st][1], A1g[st][2], A1g[st][3]);
                short8_t bb = krd(KL, rr, st * 2 + hi);
                acc0 = MFMA(a0, bb, acc0);
                acc1 = MFMA(a1, bb, acc1);
            }
#pragma unroll
            for (int r = 0; r < 16; ++r) {
                rs0[r] += __expf(acc0[r] * SCALE);
                rs1[r] += __expf(acc1[r] * SCALE);
            }
        }
        __syncthreads();   // tile kt reads done; tile kt+1 staged (vmcnt(0))
        cur ^= 1;
    }

    // column reduce over the 32 lo-lanes (k-cols live in lanes)
#pragma unroll
    for (int r = 0; r < 16; ++r) {
        float v0 = rs0[r], v1 = rs1[r];
        v0 += __shfl_xor(v0, 1);  v1 += __shfl_xor(v1, 1);
        v0 += __shfl_xor(v0, 2);  v1 += __shfl_xor(v1, 2);
        v0 += __shfl_xor(v0, 4);  v1 += __shfl_xor(v1, 4);
        v0 += __shfl_xor(v0, 8);  v1 += __shfl_xor(v1, 8);
        v0 += __shfl_xor(v0, 16); v1 += __shfl_xor(v1, 16);
        rs0[r] = v0; rs1[r] = v1;
    }
    if (lo == 0) {
#pragma unroll
        for (int r = 0; r < 16; ++r) {
            int rmap = (r & 3) + 8 * (r >> 2) + 4 * hi;
            atomicAdd(&lsum[b * NTOK + q0 + w * 64 + rmap], rs0[r]);
            atomicAdd(&lsum[b * NTOK + q0 + w * 64 + 32 + rmap], rs1[r]);
        }
    }
}

// ---------------- pass 2 (R18): w[b,k] += sum_q exp(scale*s)/l_q ----------------
// Mirror of pass 1: wave owns 64 K-rows (A-frags in AGPRs), Q streams via LDS.
__global__ __launch_bounds__(512, 2) void score_pass2(const unsigned short* __restrict__ Qbf,
                                                      const unsigned short* __restrict__ Kbf,
                                                      const float* __restrict__ lsum,
                                                      float* __restrict__ wsum) {
    const int id = blockIdx.x;
    const int xcd = id & 7, j = id >> 3;
    const int ktile = j & 7, gh = j >> 3;
    const int g = xcd * 4 + gh;
    const int qslice = g & 3, b = g >> 2;

    const int k0 = ktile * 512;
    const int qbase = qslice * 1024;
    const int t = threadIdx.x, w = t >> 6, l = t & 63, lo = l & 31, hi = l >> 5;
    const unsigned short* Qb = Qbf + (size_t)b * NTOK * HDIM;
    const unsigned short* Kb = Kbf + (size_t)b * NTOK * HDIM;
    const float* lb = lsum + (size_t)b * NTOK;

    __shared__ __align__(16) unsigned short Qbuf[2][16384];

    int soff[4];
#pragma unroll
    for (int jj = 0; jj < 4; ++jj) {
        int idx = (w * 4 + jj) * 64 + l;
        int r = (idx >> 3) & 63, dc = idx >> 9;
        int u = (idx & 7) ^ (r & 7);
        soff[jj] = r * HDIM + dc * 64 + u * 8;
    }

    const unsigned short* src = Qb + (size_t)qbase * HDIM;
    stage64(Qbuf[0], src, w, soff);
    src += 64 * HDIM;

    unsigned A0g[16][4], A1g[16][4];
    const unsigned short* krow = Kb + (size_t)(k0 + w * 64 + lo) * HDIM + hi * 8;
#pragma unroll
    for (int st = 0; st < 16; ++st) {
        sta4(A0g[st], *(const short8_t*)(krow + st * 16));
        sta4(A1g[st], *(const short8_t*)(krow + 32 * HDIM + st * 16));
    }

    float cs0[16], cs1[16];
#pragma unroll
    for (int r = 0; r < 16; ++r) { cs0[r] = 0.f; cs1[r] = 0.f; }

    __syncthreads();

    int cur = 0;
    for (int qt = 0; qt < 16; ++qt) {
        if (qt < 15) { stage64(Qbuf[cur ^ 1], src, w, soff); src += 64 * HDIM; }
        const unsigned short* QL = Qbuf[cur];
#pragma unroll
        for (int h = 0; h < 2; ++h) {
            const int rr = h * 32 + lo;
            float linv = 1.0f / lb[qbase + qt * 64 + rr];   // q-col in lane
            f32x16 acc0 = {}, acc1 = {};
#pragma unroll 4
            for (int st = 0; st < 16; ++st) {
                short8_t a0 = lda4(A0g[st][0], A0g[st][1], A0g[st][2], A0g[st][3]);
                short8_t a1 = lda4(A1g[st][0], A1g[st][1], A1g[st][2], A1g[st][3]);
                short8_t bb = krd(QL, rr, st * 2 + hi);
                acc0 = MFMA(a0, bb, acc0);
                acc1 = MFMA(a1, bb, acc1);
            }
#pragma unroll
            for (int r = 0; r < 16; ++r) {
                cs0[r] += __expf(acc0[r] * SCALE) * linv;
                cs1[r] += __expf(acc1[r] * SCALE) * linv;
            }
        }
        __syncthreads();
        cur ^= 1;
    }

#pragma unroll
    for (int r = 0; r < 16; ++r) {
        float v0 = cs0[r], v1 = cs1[r];
        v0 += __shfl_xor(v0, 1);  v1 += __shfl_xor(v1, 1);
        v0 += __shfl_xor(v0, 2);  v1 += __shfl_xor(v1, 2);
        v0 += __shfl_xor(v0, 4);  v1 += __shfl_xor(v1, 4);
        v0 += __shfl_xor(v0, 8);  v1 += __shfl_xor(v1, 8);
        v0 += __shfl_xor(v0, 16); v1 += __shfl_xor(v1, 16);
        cs0[r] = v0; cs1[r] = v1;
    }
    if (lo == 0) {
#pragma unroll
        for (int r = 0; r < 16; ++r) {
            int rmap = (r & 3) + 8 * (r >> 2) + 4 * hi;
            atomicAdd(&wsum[b * NTOK + k0 + w * 64 + rmap], cs0[r]);
            atomicAdd(&wsum[b * NTOK + k0 + w * 64 + 32 + rmap], cs1[r]);
        }
    }
}

__global__ __launch_bounds__(256) void finalize_kernel(const float* __restrict__ V,
                                                       const float* __restrict__ w,
                                                       float* __restrict__ out) {
    const int b = blockIdx.y;
    const int k0 = blockIdx.x * 256;
    const int h = threadIdx.x;
    __shared__ float wsh[256];
    wsh[h] = w[b * NTOK + k0 + h];
    __syncthreads();
    const float* Vb = V + ((size_t)b * NTOK + k0) * HDIM;
    float acc = 0.f;
#pragma unroll 4
    for (int kk = 0; kk < 256; ++kk) acc = fmaf(wsh[kk], Vb[(size_t)kk * HDIM + h], acc);
    atomicAdd(&out[b * HDIM + h], acc * (1.0f / (float)NTOK));
}

extern "C" void kernel_launch(void* const* d_in, const int* in_sizes, int n_in,
                              void* d_out, int out_size, void* d_ws, size_t ws_size,
                              hipStream_t stream) {
    const float* x  = (const float*)d_in[0];
    const float* Wq = (const float*)d_in[1];
    const float* bq = (const float*)d_in[2];
    const float* Wk = (const float*)d_in[3];
    const float* bk = (const float*)d_in[4];
    const float* Wv = (const float*)d_in[5];
    const float* bv = (const float*)d_in[6];
    float* out = (float*)d_out;

    const size_t BNH = (size_t)NBATCH * NTOK * HDIM;   // 8388608
    unsigned short* Wt  = (unsigned short*)d_ws;        // 3 transposed bf16 weights
    unsigned short* xbf = Wt + 3 * 65536;               // bf16 x
    unsigned short* Qbf = xbf + BNH;
    unsigned short* Kbf = Qbf + BNH;
    float* Vf   = (float*)(Kbf + BNH);                  // fp32 V
    float* lsum = Vf + BNH;
    float* wsum = lsum + (size_t)NBATCH * NTOK;

    zero_kernel<<<dim3(128), dim3(256), 0, stream>>>(wsum, lsum, out);
    convert_x<<<dim3(8192), dim3(256), 0, stream>>>(x, xbf);
    convert_wt<<<dim3(8, 3), dim3(256), 0, stream>>>(Wq, Wk, Wv, Wt);
    qkv_mfma<<<dim3(256, 2, 3), dim3(256), 0, stream>>>(xbf, Wt, bq, bk, bv, Qbf, Kbf, Vf);
    score_pass1<<<dim3(256), dim3(512), 0, stream>>>(Qbf, Kbf, lsum);
    score_pass2<<<dim3(256), dim3(512), 0, stream>>>(Qbf, Kbf, lsum, wsum);
    finalize_kernel<<<dim3(16, 8), dim3(256), 0, stream>>>(Vf, wsum, out);
}

// Round 9
// 288.888 us; speedup vs baseline: 3.2641x; 3.2641x over previous
//
#include <hip/hip_runtime.h>
#include <hip/hip_bf16.h>

// B=8, N=4096, D=H=256. out[b,h] = sum_k w[b,k]*V[b,k,h],
//   w[b,k] = (1/N) sum_q exp(scale*s_qk)/l_q,  l_q = sum_k exp(scale*s_qk)
// R19: 2-D wave split to get 4 waves/SIMD WITHOUT raising per-wave regs.
//      R18 failed via rule-#20 (partial unroll -> A arrays in scratch, 1GB
//      FETCH). R11's gap is TLP (no pipe >50% busy at 2 waves/SIMD).
//      Block 512thr/8w covers 128 q-rows: wave=(qset=w&3, khalf=w>>2);
//      32 A-rows/wave (64 regs), ONE acc (16 AGPR), ONE rs[16], reads only
//      its k-half (16 ds_read/tile). Demand ~105-115 < 128 -> natural
//      alloc, no spill, 2 blocks/CU co-resident (LDS 2x64KB). k-half
//      partials merge via the existing atomicAdd. Grid 512 (32 qtiles x
//      2 slices x 8 b). qkv/convert/finalize verbatim.

#define NTOK 4096
#define HDIM 256
#define NBATCH 8
#define SCALE 0.0625f  // 1/sqrt(256)

typedef __attribute__((ext_vector_type(8))) short short8_t;   // 8 bf16 (4 VGPRs)
typedef __attribute__((ext_vector_type(16))) float f32x16;    // 32x32 C/D frag

__device__ __forceinline__ unsigned short f2bf(float f) {
    unsigned u = __float_as_uint(f);
    u += 0x7fff + ((u >> 16) & 1);   // RNE
    return (unsigned short)(u >> 16);
}

#define MFMA(a, b, c) __builtin_amdgcn_mfma_f32_32x32x16_bf16(a, b, c, 0, 0, 0)

__device__ __forceinline__ void async_cp16(const void* g, void* l) {
    __builtin_amdgcn_global_load_lds((const __attribute__((address_space(1))) void*)g,
                                     (__attribute__((address_space(3))) void*)l, 16, 0, 0);
}

// ---- validated 128-row stager (used by qkv_mfma): 16B unit (r,u) -> r*8 + (u^(r&7))
__device__ __forceinline__ void stage_swz(unsigned short* lds, const unsigned short* src,
                                          int row0, int dbase, int w, int l) {
#pragma unroll
    for (int i = 0; i < 4; ++i) {
        int rloc = w * 32 + i * 8 + (l >> 3);
        int u = (l & 7) ^ (l >> 3);
        const unsigned short* g = src + (size_t)(row0 + rloc) * HDIM + dbase + u * 8;
        unsigned short* d = lds + (w * 32 + i * 8) * 64;
        async_cp16(g, d);
    }
}

__device__ __forceinline__ short8_t frd(const unsigned short* lds, int rb, int lo, int u) {
    return *(const short8_t*)(lds + ((rb * 32 + lo) * 8 + (u ^ (lo & 7))) * 8);
}

// ---- 64-row x 256-col bf16 tile stager (32KB), layout [dc][row][unit'],
//      unit' = u ^ (row&7). Per-lane element offsets precomputed in soff[4].
__device__ __forceinline__ void stage64(unsigned short* lds, const unsigned short* src,
                                        int w, const int* soff) {
#pragma unroll
    for (int j = 0; j < 4; ++j)
        async_cp16(src + soff[j], lds + (size_t)(w * 4 + j) * 512);
}

// read B-frag: row r (0..63) of resident tile, depth unit u (0..31)
__device__ __forceinline__ short8_t krd(const unsigned short* lds, int r, int u) {
    int dc = u >> 3, uu = u & 7;
    return *(const short8_t*)(lds + ((dc * 64 + r) * 8 + (uu ^ (r & 7))) * 8);
}

__global__ void zero_kernel(float* __restrict__ w, float* __restrict__ l, float* __restrict__ out) {
    int i = blockIdx.x * 256 + threadIdx.x;
    w[i] = 0.f;
    l[i] = 0.f;
    if (i < NBATCH * HDIM) out[i] = 0.f;
}

// ---------------- fp32 -> bf16 for x (once) ----------------
__global__ void convert_x(const float* __restrict__ x, unsigned short* __restrict__ xbf) {
    int i = (blockIdx.x * 256 + threadIdx.x) * 4;
    float4 v = *(const float4*)(x + i);
    ushort4 o;
    o.x = f2bf(v.x); o.y = f2bf(v.y); o.z = f2bf(v.z); o.w = f2bf(v.w);
    *(ushort4*)(xbf + i) = o;
}

__global__ void convert_wt(const float* __restrict__ Wq, const float* __restrict__ Wk,
                           const float* __restrict__ Wv, unsigned short* __restrict__ Wt) {
    int z = blockIdx.y;
    const float* W = (z == 0) ? Wq : (z == 1) ? Wk : Wv;
    unsigned short* o = Wt + z * 65536;
    int n = threadIdx.x;
    for (int kk = 0; kk < 32; ++kk) {
        int k = blockIdx.x * 32 + kk;
        o[n * 256 + k] = f2bf(W[k * 256 + n]);
    }
}

// ---------------- QKV projection (verbatim validated) ----------------
__global__ __launch_bounds__(256) void qkv_mfma(const unsigned short* __restrict__ xbf,
                                                const unsigned short* __restrict__ Wt,
                                                const float* __restrict__ bq, const float* __restrict__ bk,
                                                const float* __restrict__ bv,
                                                unsigned short* __restrict__ Qbf,
                                                unsigned short* __restrict__ Kbf,
                                                float* __restrict__ Vf) {
    const int z = blockIdx.z;
    const unsigned short* Wz = Wt + z * 65536;
    const float* bias = (z == 0) ? bq : (z == 1) ? bk : bv;
    const int m0 = blockIdx.x * 128, n0 = blockIdx.y * 128;
    const int t = threadIdx.x, w = t >> 6, l = t & 63, lo = l & 31, hi = l >> 5;
    const int rm = (w & 1) * 2, rn = (w >> 1) * 2;

    __shared__ __align__(16) char smem[32768];   // Xb 16K | Wb 16K
    unsigned short* Xb = (unsigned short*)smem;
    unsigned short* Wb = (unsigned short*)(smem + 16384);

    f32x16 acc[2][2];
#pragma unroll
    for (int a = 0; a < 2; ++a)
#pragma unroll
        for (int c = 0; c < 2; ++c)
#pragma unroll
            for (int r = 0; r < 16; ++r) acc[a][c][r] = 0.f;

    for (int dc = 0; dc < 4; ++dc) {
        __syncthreads();
        stage_swz(Xb, xbf, m0, dc * 64, w, l);
        stage_swz(Wb, Wz, n0, dc * 64, w, l);
        __syncthreads();
#pragma unroll
        for (int ks = 0; ks < 4; ++ks) {
            int u = ks * 2 + hi;
            short8_t a0 = frd(Xb, rm + 0, lo, u);
            short8_t a1 = frd(Xb, rm + 1, lo, u);
            short8_t b0 = frd(Wb, rn + 0, lo, u);
            short8_t b1 = frd(Wb, rn + 1, lo, u);
            acc[0][0] = MFMA(a0, b0, acc[0][0]);
            acc[0][1] = MFMA(a0, b1, acc[0][1]);
            acc[1][0] = MFMA(a1, b0, acc[1][0]);
            acc[1][1] = MFMA(a1, b1, acc[1][1]);
        }
    }
    float bc0 = bias[n0 + (w >> 1) * 64 + lo];
    float bc1 = bias[n0 + (w >> 1) * 64 + 32 + lo];
#pragma unroll
    for (int mb = 0; mb < 2; ++mb)
#pragma unroll
        for (int r = 0; r < 16; ++r) {
            int row = m0 + (w & 1) * 64 + mb * 32 + (r & 3) + 8 * (r >> 2) + 4 * hi;
            int c0 = n0 + (w >> 1) * 64 + lo, c1 = c0 + 32;
            float v0 = acc[mb][0][r] + bc0;
            float v1 = acc[mb][1][r] + bc1;
            if (z == 2) {
                Vf[(size_t)row * HDIM + c0] = v0;
                Vf[(size_t)row * HDIM + c1] = v1;
            } else {
                unsigned short* o = (z == 0) ? Qbf : Kbf;
                o[(size_t)row * HDIM + c0] = f2bf(v0);
                o[(size_t)row * HDIM + c1] = f2bf(v1);
            }
        }
}

// ---------------- pass 1 (R19): l[b,q] = sum_k exp(scale*s) ----------------
// Block: 512 thr / 8 waves = 4 qsets x 2 khalves over 128 q-rows.
// Wave: 32 A-rows in regs (64 VGPR), ONE acc, reads only its 32-row k-half
// of each 64-row streamed tile (16 ds_read + 16 MFMA + 16 exp per tile).
// Streams 2048 K-rows in 32 tiles (LDS dbuf 2x32KB), 1 barrier per tile.
// Demand ~110 regs < 128 -> 4 waves/SIMD, 2 blocks/CU.
__global__ __launch_bounds__(512) void score_pass1(const unsigned short* __restrict__ Qbf,
                                                   const unsigned short* __restrict__ Kbf,
                                                   float* __restrict__ lsum) {
    // XCD-chunked remap: the 32 qtile-blocks sharing one (kslice,b) K-stream
    // land on one XCD (ids congruent mod 8) -> stream re-reads are L2-hits.
    const int id = blockIdx.x;
    const int xcd = id & 7, j = id >> 3;        // j in 0..63
    const int qtile = j & 31, gh = j >> 5;      // gh in 0..1
    const int g = xcd * 2 + gh;                 // group 0..15
    const int kslice = g & 1, b = g >> 1;

    const int q0 = qtile * 128;
    const int kbase = kslice * 2048;
    const int t = threadIdx.x, w = t >> 6, l = t & 63, lo = l & 31, hi = l >> 5;
    const int qset = w & 3, khalf = w >> 2;
    const unsigned short* Qb = Qbf + (size_t)b * NTOK * HDIM;
    const unsigned short* Kb = Kbf + (size_t)b * NTOK * HDIM;

    __shared__ __align__(16) unsigned short Kbuf[2][16384];   // 2 x 32KB

    // per-lane stage offsets (elements), constant across tiles
    int soff[4];
#pragma unroll
    for (int jj = 0; jj < 4; ++jj) {
        int idx = (w * 4 + jj) * 64 + l;
        int r = (idx >> 3) & 63, dc = idx >> 9;
        int u = (idx & 7) ^ (r & 7);
        soff[jj] = r * HDIM + dc * 64 + u * 8;
    }

    const unsigned short* src = Kb + (size_t)kbase * HDIM;
    stage64(Kbuf[0], src, w, soff);                            // tile 0 in flight
    src += 64 * HDIM;

    // A-frags: 32 q-rows x 256 depth (rows q0 + qset*32 + lo)
    short8_t A[16];
    const unsigned short* qrow = Qb + (size_t)(q0 + qset * 32 + lo) * HDIM + hi * 8;
#pragma unroll
    for (int st = 0; st < 16; ++st) A[st] = *(const short8_t*)(qrow + st * 16);

    float rs[16];
#pragma unroll
    for (int r = 0; r < 16; ++r) rs[r] = 0.f;

    __syncthreads();   // drains tile-0 stage + A-loads

    const int rr = khalf * 32 + lo;   // this wave's k-row lane within the tile
    int cur = 0;
    for (int kt = 0; kt < 32; ++kt) {
        if (kt < 31) { stage64(Kbuf[cur ^ 1], src, w, soff); src += 64 * HDIM; }
        const unsigned short* KL = Kbuf[cur];
        f32x16 acc = {};
#pragma unroll
        for (int st = 0; st < 16; ++st)
            acc = MFMA(A[st], krd(KL, rr, st * 2 + hi), acc);
#pragma unroll
        for (int r = 0; r < 16; ++r) rs[r] += __expf(acc[r] * SCALE);
        __syncthreads();   // tile kt reads done; tile kt+1 staged (vmcnt(0))
        cur ^= 1;
    }

    // column reduce over the 32 lo-lanes (k-cols live in lanes);
    // khalf partner wave adds its partial via the same atomicAdd.
#pragma unroll
    for (int r = 0; r < 16; ++r) {
        float v = rs[r];
        v += __shfl_xor(v, 1);
        v += __shfl_xor(v, 2);
        v += __shfl_xor(v, 4);
        v += __shfl_xor(v, 8);
        v += __shfl_xor(v, 16);
        rs[r] = v;
    }
    if (lo == 0) {
#pragma unroll
        for (int r = 0; r < 16; ++r) {
            int row = q0 + qset * 32 + (r & 3) + 8 * (r >> 2) + 4 * hi;
            atomicAdd(&lsum[b * NTOK + row], rs[r]);
        }
    }
}

// ---------------- pass 2 (R19): w[b,k] += sum_q exp(scale*s)/l_q ----------------
// Mirror: wave owns 32 K-rows (A in regs), Q streams; qhalf = w>>2 picks the
// 32-q-col half of each tile this wave processes.
__global__ __launch_bounds__(512) void score_pass2(const unsigned short* __restrict__ Qbf,
                                                   const unsigned short* __restrict__ Kbf,
                                                   const float* __restrict__ lsum,
                                                   float* __restrict__ wsum) {
    const int id = blockIdx.x;
    const int xcd = id & 7, j = id >> 3;
    const int ktile = j & 31, gh = j >> 5;
    const int g = xcd * 2 + gh;
    const int qslice = g & 1, b = g >> 1;

    const int k0 = ktile * 128;
    const int qbase = qslice * 2048;
    const int t = threadIdx.x, w = t >> 6, l = t & 63, lo = l & 31, hi = l >> 5;
    const int kset = w & 3, qhalf = w >> 2;
    const unsigned short* Qb = Qbf + (size_t)b * NTOK * HDIM;
    const unsigned short* Kb = Kbf + (size_t)b * NTOK * HDIM;
    const float* lb = lsum + (size_t)b * NTOK;

    __shared__ __align__(16) unsigned short Qbuf[2][16384];

    int soff[4];
#pragma unroll
    for (int jj = 0; jj < 4; ++jj) {
        int idx = (w * 4 + jj) * 64 + l;
        int r = (idx >> 3) & 63, dc = idx >> 9;
        int u = (idx & 7) ^ (r & 7);
        soff[jj] = r * HDIM + dc * 64 + u * 8;
    }

    const unsigned short* src = Qb + (size_t)qbase * HDIM;
    stage64(Qbuf[0], src, w, soff);
    src += 64 * HDIM;

    short8_t A[16];
    const unsigned short* krow = Kb + (size_t)(k0 + kset * 32 + lo) * HDIM + hi * 8;
#pragma unroll
    for (int st = 0; st < 16; ++st) A[st] = *(const short8_t*)(krow + st * 16);

    float cs[16];
#pragma unroll
    for (int r = 0; r < 16; ++r) cs[r] = 0.f;

    __syncthreads();

    const int rr = qhalf * 32 + lo;   // this wave's q-col lane within the tile
    int cur = 0;
    for (int qt = 0; qt < 32; ++qt) {
        if (qt < 31) { stage64(Qbuf[cur ^ 1], src, w, soff); src += 64 * HDIM; }
        float linv = 1.0f / lb[qbase + qt * 64 + rr];
        const unsigned short* QL = Qbuf[cur];
        f32x16 acc = {};
#pragma unroll
        for (int st = 0; st < 16; ++st)
            acc = MFMA(A[st], krd(QL, rr, st * 2 + hi), acc);
#pragma unroll
        for (int r = 0; r < 16; ++r) cs[r] += __expf(acc[r] * SCALE) * linv;
        __syncthreads();
        cur ^= 1;
    }

#pragma unroll
    for (int r = 0; r < 16; ++r) {
        float v = cs[r];
        v += __shfl_xor(v, 1);
        v += __shfl_xor(v, 2);
        v += __shfl_xor(v, 4);
        v += __shfl_xor(v, 8);
        v += __shfl_xor(v, 16);
        cs[r] = v;
    }
    if (lo == 0) {
#pragma unroll
        for (int r = 0; r < 16; ++r) {
            int row = k0 + kset * 32 + (r & 3) + 8 * (r >> 2) + 4 * hi;
            atomicAdd(&wsum[b * NTOK + row], cs[r]);
        }
    }
}

__global__ __launch_bounds__(256) void finalize_kernel(const float* __restrict__ V,
                                                       const float* __restrict__ w,
                                                       float* __restrict__ out) {
    const int b = blockIdx.y;
    const int k0 = blockIdx.x * 256;
    const int h = threadIdx.x;
    __shared__ float wsh[256];
    wsh[h] = w[b * NTOK + k0 + h];
    __syncthreads();
    const float* Vb = V + ((size_t)b * NTOK + k0) * HDIM;
    float acc = 0.f;
#pragma unroll 4
    for (int kk = 0; kk < 256; ++kk) acc = fmaf(wsh[kk], Vb[(size_t)kk * HDIM + h], acc);
    atomicAdd(&out[b * HDIM + h], acc * (1.0f / (float)NTOK));
}

extern "C" void kernel_launch(void* const* d_in, const int* in_sizes, int n_in,
                              void* d_out, int out_size, void* d_ws, size_t ws_size,
                              hipStream_t stream) {
    const float* x  = (const float*)d_in[0];
    const float* Wq = (const float*)d_in[1];
    const float* bq = (const float*)d_in[2];
    const float* Wk = (const float*)d_in[3];
    const float* bk = (const float*)d_in[4];
    const float* Wv = (const float*)d_in[5];
    const float* bv = (const float*)d_in[6];
    float* out = (float*)d_out;

    const size_t BNH = (size_t)NBATCH * NTOK * HDIM;   // 8388608
    unsigned short* Wt  = (unsigned short*)d_ws;        // 3 transposed bf16 weights
    unsigned short* xbf = Wt + 3 * 65536;               // bf16 x
    unsigned short* Qbf = xbf + BNH;
    unsigned short* Kbf = Qbf + BNH;
    float* Vf   = (float*)(Kbf + BNH);                  // fp32 V
    float* lsum = Vf + BNH;
    float* wsum = lsum + (size_t)NBATCH * NTOK;

    zero_kernel<<<dim3(128), dim3(256), 0, stream>>>(wsum, lsum, out);
    convert_x<<<dim3(8192), dim3(256), 0, stream>>>(x, xbf);
    convert_wt<<<dim3(8, 3), dim3(256), 0, stream>>>(Wq, Wk, Wv, Wt);
    qkv_mfma<<<dim3(256, 2, 3), dim3(256), 0, stream>>>(xbf, Wt, bq, bk, bv, Qbf, Kbf, Vf);
    score_pass1<<<dim3(512), dim3(512), 0, stream>>>(Qbf, Kbf, lsum);
    score_pass2<<<dim3(512), dim3(512), 0, stream>>>(Qbf, Kbf, lsum, wsum);
    finalize_kernel<<<dim3(16, 8), dim3(256), 0, stream>>>(Vf, wsum, out);
}